// Round 4
// baseline (477.734 us; speedup 1.0000x reference)
//
#include <hip/hip_runtime.h>
#include <math.h>

typedef float    float4_t __attribute__((ext_vector_type(4)));
typedef _Float16 half8    __attribute__((ext_vector_type(8)));
typedef _Float16 half4_t  __attribute__((ext_vector_type(4)));

// ---------------- Kernel P: fused h-GEMM + s1/s2 + hT(fp16) ------------------
__global__ __launch_bounds__(256) void k_prep(const float* __restrict__ inp,
                                              const float* __restrict__ W,
                                              const float* __restrict__ a,
                                              float* __restrict__ s1,
                                              float* __restrict__ s2,
                                              _Float16* __restrict__ hT) {
    __shared__ float sA[32 * 68];
    __shared__ float sW[64 * 128];
    const int t   = threadIdx.x;
    const int gr0 = blockIdx.x * 32;          // global row base (0..16383)
    const int b   = gr0 >> 12;                // batch
    const int f0  = (t & 15) * 8;
    const int r0  = (t >> 4) * 2;
    float4_t acc0[2] = {}; float4_t acc1[2] = {};
    for (int kc = 0; kc < 4; ++kc) {
        __syncthreads();
        #pragma unroll
        for (int it = 0; it < 2; ++it) {      // stage inp 32x64
            int fi = it * 256 + t; int r = fi >> 4; int c = (fi & 15) * 4;
            *(float4_t*)&sA[r * 68 + c] =
                *(const float4_t*)&inp[(size_t)(gr0 + r) * 256 + kc * 64 + c];
        }
        #pragma unroll
        for (int it = 0; it < 8; ++it) {      // stage W 64x128
            int fi = it * 256 + t; int k = fi >> 5; int c = (fi & 31) * 4;
            *(float4_t*)&sW[k * 128 + c] =
                *(const float4_t*)&W[(size_t)(kc * 64 + k) * 128 + c];
        }
        __syncthreads();
        for (int k = 0; k < 64; ++k) {
            float4_t w0 = *(const float4_t*)&sW[k * 128 + f0];
            float4_t w1 = *(const float4_t*)&sW[k * 128 + f0 + 4];
            #pragma unroll
            for (int r = 0; r < 2; ++r) {
                float av = sA[(r0 + r) * 68 + k];
                acc0[r] += av * w0; acc1[r] += av * w1;
            }
        }
    }
    float4_t a1lo = *(const float4_t*)&a[f0];
    float4_t a1hi = *(const float4_t*)&a[f0 + 4];
    float4_t a2lo = *(const float4_t*)&a[128 + f0];
    float4_t a2hi = *(const float4_t*)&a[128 + f0 + 4];
    #pragma unroll
    for (int r = 0; r < 2; ++r) {
        const int row  = gr0 + r0 + r;
        const int rloc = row & 4095;
        #pragma unroll
        for (int c = 0; c < 4; ++c) {
            hT[(size_t)b * (128 * 4096) + (size_t)(f0 + c) * 4096 + rloc]     = (_Float16)acc0[r][c];
            hT[(size_t)b * (128 * 4096) + (size_t)(f0 + 4 + c) * 4096 + rloc] = (_Float16)acc1[r][c];
        }
        float p1 = acc0[r][0]*a1lo[0] + acc0[r][1]*a1lo[1] + acc0[r][2]*a1lo[2] + acc0[r][3]*a1lo[3]
                 + acc1[r][0]*a1hi[0] + acc1[r][1]*a1hi[1] + acc1[r][2]*a1hi[2] + acc1[r][3]*a1hi[3];
        float p2 = acc0[r][0]*a2lo[0] + acc0[r][1]*a2lo[1] + acc0[r][2]*a2lo[2] + acc0[r][3]*a2lo[3]
                 + acc1[r][0]*a2hi[0] + acc1[r][1]*a2hi[1] + acc1[r][2]*a2hi[2] + acc1[r][3]*a2hi[3];
        #pragma unroll
        for (int o = 1; o < 16; o <<= 1) { p1 += __shfl_xor(p1, o); p2 += __shfl_xor(p2, o); }
        if ((t & 15) == 0) { s1[row] = p1; s2[row] = p2; }
    }
}

// ---------------- Kernel M: per-batch s2 max ---------------------------------
__global__ __launch_bounds__(256) void k_s2max(const float* __restrict__ s2,
                                               float* __restrict__ s2max) {
    const int b = blockIdx.x, t = threadIdx.x;
    float m = -INFINITY;
    for (int i = t; i < 4096; i += 256) m = fmaxf(m, s2[b * 4096 + i]);
    #pragma unroll
    for (int o = 1; o < 64; o <<= 1) m = fmaxf(m, __shfl_xor(m, o));
    __shared__ float sm[4];
    if ((t & 63) == 0) sm[t >> 6] = m;
    __syncthreads();
    if (t == 0) s2max[b] = fmaxf(fmaxf(sm[0], sm[1]), fmaxf(sm[2], sm[3]));
}

// ---------------- Kernel F: fixed-max attention + P@H ------------------------
// RESTRUCTURED: 256 blocks x 1024 threads (16 waves) = exactly 1 block/CU.
// Block = 256 rows x 1024-j split. hbuf stages a 256j x 128f hT slice (64 KB)
// once per 4 wave-iterations; between stage barriers the 16 waves run with
// ZERO inter-wave synchronization (pbuf is wave-private -> lgkmcnt(0) only;
// hbuf read-only). 7 barriers total per block instead of 16 lockstep ones;
// 4 free-running waves/SIMD hide adj HBM latency. adj/s2 use a single
// consume-then-refill register set (round-2 lesson: 2 sets => spill).
// Fragment layouts / xor swizzles identical to the verified round-0 kernel.
__global__ __launch_bounds__(1024) void k_flash(const float* __restrict__ adj,
                                                const _Float16* __restrict__ hT,
                                                const float* __restrict__ s1,
                                                const float* __restrict__ s2,
                                                const float* __restrict__ s2max,
                                                float* __restrict__ part_acc,
                                                float* __restrict__ part_l) {
    __shared__ _Float16 hbuf[4 * 128 * 64];   // 64 KB: 4 subtiles x 128f x 64j
    __shared__ _Float16 pbuf[16][16 * 64];    // 32 KB: wave-private P tiles

    const int t    = threadIdx.x;
    const int bid  = blockIdx.x;
    const int sp   = bid & 3;                 // j-split
    const int rbb  = (bid >> 2) & 15;         // 256-row block within batch
    const int b    = bid >> 6;                // batch
    const int w    = t >> 6, lane = t & 63;
    const int quad = lane >> 4, ln15 = lane & 15;
    const int g    = quad;                    // row-group for p-compute
    const int cl   = ln15;                    // col-lane for p-compute
    const int rowb = rbb * 256 + w * 16;      // wave's 16-row base
    const float*    adj_w = adj + (size_t)b * 4096 * 4096 + (size_t)rowb * 4096;
    const _Float16* hT_b  = hT + (size_t)b * 128 * 4096;
    const float*    s2_b  = s2 + b * 4096;
    const float     s2m   = s2max[b];
    const int jwbase = sp * 1024;

    float s1r[4], mh[4];
    #pragma unroll
    for (int L = 0; L < 4; ++L) {
        s1r[L] = s1[b * 4096 + rowb + L * 4 + g];
        mh[L]  = fmaxf(0.f, s1r[L] + s2m);
    }

    // hbuf staging geometry: thread covers f-row t>>3, j-chunk t&7, 4 subtiles
    const int sf  = t >> 3;                   // 0..127
    const int sc  = t & 7;
    const int fb7 = ln15 & 7;

    float4_t acc[8] = {};
    float4_t psacc = {0.f, 0.f, 0.f, 0.f};
    float4_t av[4];
    float4_t s2v;

    // ---- prologue: adj/s2 for it=0 ----
    #pragma unroll
    for (int L = 0; L < 4; ++L)
        av[L] = *(const float4_t*)&adj_w[(size_t)(L * 4 + g) * 4096 + jwbase + cl * 4];
    s2v = *(const float4_t*)&s2_b[jwbase + cl * 4];

    #pragma unroll 1
    for (int st = 0; st < 4; ++st) {
        if (st) __syncthreads();              // all waves done reading hbuf
        // ---- stage 256j x 128f hT slice (64 KB) ----
        {
            const int stb = jwbase + st * 256;
            half8 hreg[4];
            #pragma unroll
            for (int i = 0; i < 4; ++i)
                hreg[i] = *(const half8*)&hT_b[(size_t)sf * 4096 + stb + i * 64 + sc * 8];
            #pragma unroll
            for (int i = 0; i < 4; ++i)
                hbuf[(i * 128 + sf) * 64 + ((sc ^ (sf & 7)) << 3)] = hreg[i][0],
                *(half8*)&hbuf[(i * 128 + sf) * 64 + ((sc ^ (sf & 7)) << 3)] = hreg[i];
        }
        __syncthreads();                      // hbuf ready
        // ---- 4 wave-iterations, barrier-free ----
        #pragma unroll
        for (int q = 0; q < 4; ++q) {
            const int it = st * 4 + q;
            const int j0 = jwbase + it * 64;
            // p = exp(adj*leaky(s1+s2) - mhat) -> wave-private pbuf
            #pragma unroll
            for (int L = 0; L < 4; ++L) {
                half4_t qv;
                #pragma unroll
                for (int c = 0; c < 4; ++c) {
                    float x = s1r[L] + s2v[c];
                    float e = x > 0.f ? x : 0.2f * x;
                    float p = av[L][c] > 0.f ? __expf(fmaf(av[L][c], e, -mh[L])) : 0.f;
                    _Float16 qq = (_Float16)p;
                    qv[c] = qq;
                    psacc[L] += (float)qq;
                }
                const int r     = L * 4 + g;
                const int c0    = cl * 4;
                const int chunk = (c0 >> 3) ^ (r & 7);
                *(half4_t*)&pbuf[w][r * 64 + chunk * 8 + (c0 & 7)] = qv;
            }
            // refill adj/s2 for next iteration (single reg set, no spill)
            if (it < 15) {
                #pragma unroll
                for (int L = 0; L < 4; ++L)
                    av[L] = *(const float4_t*)&adj_w[(size_t)(L * 4 + g) * 4096 + j0 + 64 + cl * 4];
                s2v = *(const float4_t*)&s2_b[j0 + 64 + cl * 4];
            }
            // wave-private pbuf: visible to this wave after lgkmcnt(0)
            asm volatile("s_waitcnt lgkmcnt(0)" ::: "memory");
            // A-frags from pbuf, B-frags from hbuf subtile q, MFMA
            half8 afrag[2];
            #pragma unroll
            for (int kc = 0; kc < 2; ++kc) {
                const int chunk = ((kc << 2) + quad) ^ (ln15 & 7);
                afrag[kc] = *(const half8*)&pbuf[w][ln15 * 64 + chunk * 8];
            }
            const _Float16* hsub = &hbuf[q * 128 * 64];
            #pragma unroll
            for (int nt = 0; nt < 8; ++nt) {
                #pragma unroll
                for (int kc = 0; kc < 2; ++kc) {
                    const int fb = nt * 16 + ln15;
                    half8 bfrag = *(const half8*)&hsub[fb * 64 + ((((kc << 2) + quad) ^ fb7) << 3)];
                    acc[nt] = __builtin_amdgcn_mfma_f32_16x16x32_f16(afrag[kc], bfrag, acc[nt], 0, 0, 0);
                }
            }
        }
    }

    // ---- epilogue: reduce l within each 16-lane group, write partials ----
    #pragma unroll
    for (int o = 1; o < 16; o <<= 1) {
        #pragma unroll
        for (int L = 0; L < 4; ++L) psacc[L] += __shfl_xor(psacc[L], o);
    }
    const size_t growb = (size_t)b * 4096 + rowb;
    if (cl == 0) {
        #pragma unroll
        for (int L = 0; L < 4; ++L)
            part_l[(size_t)sp * 16384 + growb + L * 4 + g] = psacc[L];
    }
    float* pacc = part_acc + (size_t)sp * 16384 * 128;
    #pragma unroll
    for (int nt = 0; nt < 8; ++nt) {
        #pragma unroll
        for (int reg = 0; reg < 4; ++reg) {
            pacc[(growb + quad * 4 + reg) * 128 + nt * 16 + ln15] = acc[nt][reg];
        }
    }
}

// ---------------- Kernel E: sum 4 j-split partials, normalize, elu -----------
__global__ __launch_bounds__(256) void k_combine(const float* __restrict__ part_acc,
                                                 const float* __restrict__ part_l,
                                                 float* __restrict__ out) {
    const int idx = blockIdx.x * 256 + threadIdx.x;   // 0..524287
    const int e0  = idx * 4;
    const int gr  = e0 >> 7;
    float l = part_l[gr] + part_l[16384 + gr] + part_l[32768 + gr] + part_l[49152 + gr];
    float4_t a0 = *(const float4_t*)&part_acc[e0];
    float4_t a1 = *(const float4_t*)&part_acc[2097152 + e0];
    float4_t a2 = *(const float4_t*)&part_acc[4194304 + e0];
    float4_t a3 = *(const float4_t*)&part_acc[6291456 + e0];
    float4_t s  = (a0 + a1) + (a2 + a3);
    float rl = 1.f / l;
    float4_t o;
    #pragma unroll
    for (int c = 0; c < 4; ++c) {
        float v = s[c] * rl;
        o[c] = v > 0.f ? v : expm1f(v);
    }
    *(float4_t*)&((float*)out)[e0] = o;
}

extern "C" void kernel_launch(void* const* d_in, const int* in_sizes, int n_in,
                              void* d_out, int out_size, void* d_ws, size_t ws_size,
                              hipStream_t stream) {
    const float* inp = (const float*)d_in[0];   // (4,4096,256)
    const float* adj = (const float*)d_in[1];   // (4,4096,4096)
    const float* W   = (const float*)d_in[2];   // (256,128)
    const float* a   = (const float*)d_in[3];   // (256,1)
    float* out = (float*)d_out;                 // (4,4096,128)

    char* wsb = (char*)d_ws;
    _Float16* hT       = (_Float16*)(wsb);                // 4 MB
    float*    s1       = (float*)(wsb + 4194304);         // 64 KB
    float*    s2       = (float*)(wsb + 4259840);         // 64 KB
    float*    s2max    = (float*)(wsb + 4325376);         // 256 B
    float*    part_l   = (float*)(wsb + 4325632);         // 256 KB
    float*    part_acc = (float*)(wsb + 4587776);         // 32 MB (total ~36.4 MB)

    hipLaunchKernelGGL(k_prep,    dim3(512),  dim3(256), 0, stream, inp, W, a, s1, s2, hT);
    hipLaunchKernelGGL(k_s2max,   dim3(4),    dim3(256), 0, stream, s2, s2max);
    hipLaunchKernelGGL(k_flash,   dim3(256),  dim3(1024), 0, stream, adj, hT, s1, s2, s2max,
                       part_acc, part_l);
    hipLaunchKernelGGL(k_combine, dim3(2048), dim3(256), 0, stream, part_acc, part_l, out);
}

// Round 6
// 429.662 us; speedup vs baseline: 1.1119x; 1.1119x over previous
//
#include <hip/hip_runtime.h>
#include <math.h>

typedef float    float4_t __attribute__((ext_vector_type(4)));
typedef _Float16 half8    __attribute__((ext_vector_type(8)));
typedef _Float16 half4_t  __attribute__((ext_vector_type(4)));

// async global->LDS, 16B per lane, zero VGPR cost. LDS dest must be
// wave-uniform base (+lane*16 implicit); global src is per-lane.
#define GLL16(G, L) __builtin_amdgcn_global_load_lds(                        \
    (const __attribute__((address_space(1))) unsigned int*)(G),              \
    (__attribute__((address_space(3))) unsigned int*)(L), 16, 0, 0)

// ---------------- Kernel P: fused h-GEMM + s1/s2 + hT(fp16) ------------------
__global__ __launch_bounds__(256) void k_prep(const float* __restrict__ inp,
                                              const float* __restrict__ W,
                                              const float* __restrict__ a,
                                              float* __restrict__ s1,
                                              float* __restrict__ s2,
                                              _Float16* __restrict__ hT) {
    __shared__ float sA[32 * 68];
    __shared__ float sW[64 * 128];
    const int t   = threadIdx.x;
    const int gr0 = blockIdx.x * 32;          // global row base (0..16383)
    const int b   = gr0 >> 12;                // batch
    const int f0  = (t & 15) * 8;
    const int r0  = (t >> 4) * 2;
    float4_t acc0[2] = {}; float4_t acc1[2] = {};
    for (int kc = 0; kc < 4; ++kc) {
        __syncthreads();
        #pragma unroll
        for (int it = 0; it < 2; ++it) {      // stage inp 32x64
            int fi = it * 256 + t; int r = fi >> 4; int c = (fi & 15) * 4;
            *(float4_t*)&sA[r * 68 + c] =
                *(const float4_t*)&inp[(size_t)(gr0 + r) * 256 + kc * 64 + c];
        }
        #pragma unroll
        for (int it = 0; it < 8; ++it) {      // stage W 64x128
            int fi = it * 256 + t; int k = fi >> 5; int c = (fi & 31) * 4;
            *(float4_t*)&sW[k * 128 + c] =
                *(const float4_t*)&W[(size_t)(kc * 64 + k) * 128 + c];
        }
        __syncthreads();
        for (int k = 0; k < 64; ++k) {
            float4_t w0 = *(const float4_t*)&sW[k * 128 + f0];
            float4_t w1 = *(const float4_t*)&sW[k * 128 + f0 + 4];
            #pragma unroll
            for (int r = 0; r < 2; ++r) {
                float av = sA[(r0 + r) * 68 + k];
                acc0[r] += av * w0; acc1[r] += av * w1;
            }
        }
    }
    float4_t a1lo = *(const float4_t*)&a[f0];
    float4_t a1hi = *(const float4_t*)&a[f0 + 4];
    float4_t a2lo = *(const float4_t*)&a[128 + f0];
    float4_t a2hi = *(const float4_t*)&a[128 + f0 + 4];
    #pragma unroll
    for (int r = 0; r < 2; ++r) {
        const int row  = gr0 + r0 + r;
        const int rloc = row & 4095;
        #pragma unroll
        for (int c = 0; c < 4; ++c) {
            hT[(size_t)b * (128 * 4096) + (size_t)(f0 + c) * 4096 + rloc]     = (_Float16)acc0[r][c];
            hT[(size_t)b * (128 * 4096) + (size_t)(f0 + 4 + c) * 4096 + rloc] = (_Float16)acc1[r][c];
        }
        float p1 = acc0[r][0]*a1lo[0] + acc0[r][1]*a1lo[1] + acc0[r][2]*a1lo[2] + acc0[r][3]*a1lo[3]
                 + acc1[r][0]*a1hi[0] + acc1[r][1]*a1hi[1] + acc1[r][2]*a1hi[2] + acc1[r][3]*a1hi[3];
        float p2 = acc0[r][0]*a2lo[0] + acc0[r][1]*a2lo[1] + acc0[r][2]*a2lo[2] + acc0[r][3]*a2lo[3]
                 + acc1[r][0]*a2hi[0] + acc1[r][1]*a2hi[1] + acc1[r][2]*a2hi[2] + acc1[r][3]*a2hi[3];
        #pragma unroll
        for (int o = 1; o < 16; o <<= 1) { p1 += __shfl_xor(p1, o); p2 += __shfl_xor(p2, o); }
        if ((t & 15) == 0) { s1[row] = p1; s2[row] = p2; }
    }
}

// ---------------- Kernel M: per-batch s2 max ---------------------------------
__global__ __launch_bounds__(256) void k_s2max(const float* __restrict__ s2,
                                               float* __restrict__ s2max) {
    const int b = blockIdx.x, t = threadIdx.x;
    float m = -INFINITY;
    for (int i = t; i < 4096; i += 256) m = fmaxf(m, s2[b * 4096 + i]);
    #pragma unroll
    for (int o = 1; o < 64; o <<= 1) m = fmaxf(m, __shfl_xor(m, o));
    __shared__ float sm[4];
    if ((t & 63) == 0) sm[t >> 6] = m;
    __syncthreads();
    if (t == 0) s2max[b] = fmaxf(fmaxf(sm[0], sm[1]), fmaxf(sm[2], sm[3]));
}

// ---------------- Kernel F: fixed-max attention + P@H ------------------------
// Grid 1024 x 256 (4 j-splits x 64 row-blocks x 4 batches). Wave = 16 rows.
// r6 = r5 + the missing END-OF-READ barrier (B2). Race in r5: gll writes to
// hbuf[cur^1] issued at top of iter jt could land while OTHER waves were
// still doing iter jt-1's MFMA reads of hbuf[cur^1] (cross-wave WAR).
// Ordering now: B2(jt) = all waves done reading slot cur  ->  top of jt+1
// may issue gll into slot cur; per-wave vmcnt(8) + B1 = data landed before
// reads. gll ops stay in flight across BOTH barriers (counted vmcnt, never
// 0 in main loop) -- the m201-proven pattern. Zero register prefetch state
// -> no spill (the r2/r4 killer). LDS 76 KB -> 2 blocks/CU.
__global__ __launch_bounds__(256, 2) void k_flash(const float* __restrict__ adj,
                                                  const _Float16* __restrict__ hT,
                                                  const float* __restrict__ s1,
                                                  const float* __restrict__ s2,
                                                  const float* __restrict__ s2max,
                                                  float* __restrict__ part_acc,
                                                  float* __restrict__ part_l) {
    __shared__ _Float16 hbuf[2][128 * 64];     // 32 KB shared hT dbuf (swizzled)
    __shared__ float    adjbuf[4][2][16 * 64]; // 32 KB wave-private adj dbuf
    __shared__ _Float16 pbuf[4][16 * 64];      // 8 KB wave-private P tiles
    __shared__ float    s2buf[1024];           // 4 KB block j-window of s2

    const int t    = threadIdx.x;
    const int bid  = blockIdx.x;
    const int sp   = bid & 3;                 // j-split
    const int rb   = (bid >> 2) & 63;         // 64-row block within batch
    const int b    = bid >> 8;                // batch
    const int w    = t >> 6, lane = t & 63;
    const int quad = lane >> 4, ln15 = lane & 15;
    const int g    = quad;                    // row-group for p-compute
    const int cl   = ln15;                    // col-lane for p-compute
    const int rowb = rb * 64 + w * 16;        // wave's 16-row base
    const float*    adj_w = adj + (size_t)b * 4096 * 4096 + (size_t)rowb * 4096;
    const _Float16* hT_b  = hT + (size_t)b * 128 * 4096;
    const float     s2m   = s2max[b];
    const int jwbase = sp * 1024;
    const int fb7 = ln15 & 7;

    float s1r[4], mh[4];
    #pragma unroll
    for (int L = 0; L < 4; ++L) {
        s1r[L] = s1[b * 4096 + rowb + L * 4 + g];
        mh[L]  = fmaxf(0.f, s1r[L] + s2m);
    }

    // ---- stage s2 window once (register load -> LDS; visible after B1(0)) --
    *(float4_t*)&s2buf[t * 4] = *(const float4_t*)&s2[(size_t)b * 4096 + jwbase + t * 4];
    asm volatile("s_waitcnt lgkmcnt(0)" ::: "memory");

    float4_t acc[8] = {};
    float4_t psacc = {0.f, 0.f, 0.f, 0.f};

    // ---- gll staging: 4 adj + 4 hT insts per wave, zero VGPR ----
    auto stage = [&](int slot, int j0) {
        // adj: wave-private linear [16][64] tile; inst i covers rows 4i..4i+3
        #pragma unroll
        for (int i = 0; i < 4; ++i) {
            const int r = i * 4 + (lane >> 4);
            GLL16(adj_w + (size_t)r * 4096 + j0 + ((lane & 15) << 2),
                  &adjbuf[w][slot][i * 256]);
        }
        // hT: shared swizzled tile; wave w covers f-rows 32w..32w+31
        #pragma unroll
        for (int i = 0; i < 4; ++i) {
            const int f0r = (w * 4 + i) * 8;          // 8 f-rows per inst
            const int f   = f0r + (lane >> 3);
            const int sch = (lane & 7) ^ (f & 7);     // inverse-swizzled source
            GLL16(hT_b + ((size_t)f << 12) + j0 + (sch << 3),
                  &hbuf[slot][f0r * 64]);
        }
    };

    asm volatile("" ::: "memory");
    stage(0, jwbase);                          // gll(0): 8 ops in flight

    #pragma unroll 1
    for (int jt = 0; jt < 16; ++jt) {
        const int cur = jt & 1;
        const int j0  = jwbase + jt * 64;
        // ---- issue gll(jt+1) into slot cur^1 (freed by B2 of iter jt-1) ----
        if (jt < 15) stage(cur ^ 1, j0 + 64);
        // counted wait: drain gll(jt)'s 8, leave gll(jt+1)'s 8 in flight
        if (jt < 15) asm volatile("s_waitcnt vmcnt(8)" ::: "memory");
        else         asm volatile("s_waitcnt vmcnt(0)" ::: "memory");
        __builtin_amdgcn_s_barrier();          // B1: slot-cur data visible
        asm volatile("" ::: "memory");
        // ---- p = exp(adj*leaky(s1+s2) - mhat) from LDS -> pbuf ----
        #pragma unroll
        for (int L = 0; L < 4; ++L) {
            float4_t av  = *(const float4_t*)&adjbuf[w][cur][(L * 4 + g) * 64 + cl * 4];
            float4_t s2v = *(const float4_t*)&s2buf[jt * 64 + cl * 4];
            half4_t qv;
            #pragma unroll
            for (int c = 0; c < 4; ++c) {
                float x = s1r[L] + s2v[c];
                float e = x > 0.f ? x : 0.2f * x;
                float p = av[c] > 0.f ? __expf(fmaf(av[c], e, -mh[L])) : 0.f;
                _Float16 q = (_Float16)p;
                qv[c] = q;
                psacc[L] += (float)q;
            }
            const int r     = L * 4 + g;
            const int c0    = cl * 4;
            const int chunk = (c0 >> 3) ^ (r & 7);
            *(half4_t*)&pbuf[w][r * 64 + chunk * 8 + (c0 & 7)] = qv;
        }
        // wave-private pbuf: visible to this wave after lgkmcnt(0)
        asm volatile("s_waitcnt lgkmcnt(0)" ::: "memory");
        // ---- A-frags from pbuf, B-frags from hbuf[cur], MFMA ----
        half8 afrag[2];
        #pragma unroll
        for (int kc = 0; kc < 2; ++kc) {
            const int chunk = ((kc << 2) + quad) ^ (ln15 & 7);
            afrag[kc] = *(const half8*)&pbuf[w][ln15 * 64 + chunk * 8];
        }
        #pragma unroll
        for (int nt = 0; nt < 8; ++nt) {
            #pragma unroll
            for (int kc = 0; kc < 2; ++kc) {
                const int fb = nt * 16 + ln15;
                half8 bfrag = *(const half8*)&hbuf[cur][fb * 64 + ((((kc << 2) + quad) ^ fb7) << 3)];
                acc[nt] = __builtin_amdgcn_mfma_f32_16x16x32_f16(afrag[kc], bfrag, acc[nt], 0, 0, 0);
            }
        }
        // ---- B2: all waves done reading slot cur -> writable next iter ----
        if (jt < 15) {
            asm volatile("" ::: "memory");
            __builtin_amdgcn_s_barrier();
        }
    }

    // ---- epilogue: reduce l within each 16-lane group, write partials ----
    #pragma unroll
    for (int o = 1; o < 16; o <<= 1) {
        #pragma unroll
        for (int L = 0; L < 4; ++L) psacc[L] += __shfl_xor(psacc[L], o);
    }
    const size_t growb = (size_t)b * 4096 + rowb;
    if (cl == 0) {
        #pragma unroll
        for (int L = 0; L < 4; ++L)
            part_l[(size_t)sp * 16384 + growb + L * 4 + g] = psacc[L];
    }
    float* pacc = part_acc + (size_t)sp * 16384 * 128;
    #pragma unroll
    for (int nt = 0; nt < 8; ++nt) {
        #pragma unroll
        for (int reg = 0; reg < 4; ++reg) {
            pacc[(growb + quad * 4 + reg) * 128 + nt * 16 + ln15] = acc[nt][reg];
        }
    }
}

// ---------------- Kernel E: sum 4 j-split partials, normalize, elu -----------
__global__ __launch_bounds__(256) void k_combine(const float* __restrict__ part_acc,
                                                 const float* __restrict__ part_l,
                                                 float* __restrict__ out) {
    const int idx = blockIdx.x * 256 + threadIdx.x;   // 0..524287
    const int e0  = idx * 4;
    const int gr  = e0 >> 7;
    float l = part_l[gr] + part_l[16384 + gr] + part_l[32768 + gr] + part_l[49152 + gr];
    float4_t a0 = *(const float4_t*)&part_acc[e0];
    float4_t a1 = *(const float4_t*)&part_acc[2097152 + e0];
    float4_t a2 = *(const float4_t*)&part_acc[4194304 + e0];
    float4_t a3 = *(const float4_t*)&part_acc[6291456 + e0];
    float4_t s  = (a0 + a1) + (a2 + a3);
    float rl = 1.f / l;
    float4_t o;
    #pragma unroll
    for (int c = 0; c < 4; ++c) {
        float v = s[c] * rl;
        o[c] = v > 0.f ? v : expm1f(v);
    }
    *(float4_t*)&((float*)out)[e0] = o;
}

extern "C" void kernel_launch(void* const* d_in, const int* in_sizes, int n_in,
                              void* d_out, int out_size, void* d_ws, size_t ws_size,
                              hipStream_t stream) {
    const float* inp = (const float*)d_in[0];   // (4,4096,256)
    const float* adj = (const float*)d_in[1];   // (4,4096,4096)
    const float* W   = (const float*)d_in[2];   // (256,128)
    const float* a   = (const float*)d_in[3];   // (256,1)
    float* out = (float*)d_out;                 // (4,4096,128)

    char* wsb = (char*)d_ws;
    _Float16* hT       = (_Float16*)(wsb);                // 4 MB
    float*    s1       = (float*)(wsb + 4194304);         // 64 KB
    float*    s2       = (float*)(wsb + 4259840);         // 64 KB
    float*    s2max    = (float*)(wsb + 4325376);         // 256 B
    float*    part_l   = (float*)(wsb + 4325632);         // 256 KB
    float*    part_acc = (float*)(wsb + 4587776);         // 32 MB (total ~36.4 MB)

    hipLaunchKernelGGL(k_prep,    dim3(512),  dim3(256), 0, stream, inp, W, a, s1, s2, hT);
    hipLaunchKernelGGL(k_s2max,   dim3(4),    dim3(256), 0, stream, s2, s2max);
    hipLaunchKernelGGL(k_flash,   dim3(1024), dim3(256), 0, stream, adj, hT, s1, s2, s2max,
                       part_acc, part_l);
    hipLaunchKernelGGL(k_combine, dim3(2048), dim3(256), 0, stream, part_acc, part_l, out);
}

// Round 7
// 428.418 us; speedup vs baseline: 1.1151x; 1.0029x over previous
//
#include <hip/hip_runtime.h>
#include <math.h>

typedef float    float4_t __attribute__((ext_vector_type(4)));
typedef _Float16 half8    __attribute__((ext_vector_type(8)));
typedef _Float16 half4_t  __attribute__((ext_vector_type(4)));

// async global->LDS, 16B per lane, zero VGPR cost. LDS dest must be
// wave-uniform base (+lane*16 implicit); global src is per-lane.
#define GLL16(G, L) __builtin_amdgcn_global_load_lds(                        \
    (const __attribute__((address_space(1))) unsigned int*)(G),              \
    (__attribute__((address_space(3))) unsigned int*)(L), 16, 0, 0)

// ---------------- Kernel P: fused h-GEMM + s1/s2 + hT(fp16) ------------------
__global__ __launch_bounds__(256) void k_prep(const float* __restrict__ inp,
                                              const float* __restrict__ W,
                                              const float* __restrict__ a,
                                              float* __restrict__ s1,
                                              float* __restrict__ s2,
                                              _Float16* __restrict__ hT) {
    __shared__ float sA[32 * 68];
    __shared__ float sW[64 * 128];
    const int t   = threadIdx.x;
    const int gr0 = blockIdx.x * 32;          // global row base (0..16383)
    const int b   = gr0 >> 12;                // batch
    const int f0  = (t & 15) * 8;
    const int r0  = (t >> 4) * 2;
    float4_t acc0[2] = {}; float4_t acc1[2] = {};
    for (int kc = 0; kc < 4; ++kc) {
        __syncthreads();
        #pragma unroll
        for (int it = 0; it < 2; ++it) {      // stage inp 32x64
            int fi = it * 256 + t; int r = fi >> 4; int c = (fi & 15) * 4;
            *(float4_t*)&sA[r * 68 + c] =
                *(const float4_t*)&inp[(size_t)(gr0 + r) * 256 + kc * 64 + c];
        }
        #pragma unroll
        for (int it = 0; it < 8; ++it) {      // stage W 64x128
            int fi = it * 256 + t; int k = fi >> 5; int c = (fi & 31) * 4;
            *(float4_t*)&sW[k * 128 + c] =
                *(const float4_t*)&W[(size_t)(kc * 64 + k) * 128 + c];
        }
        __syncthreads();
        for (int k = 0; k < 64; ++k) {
            float4_t w0 = *(const float4_t*)&sW[k * 128 + f0];
            float4_t w1 = *(const float4_t*)&sW[k * 128 + f0 + 4];
            #pragma unroll
            for (int r = 0; r < 2; ++r) {
                float av = sA[(r0 + r) * 68 + k];
                acc0[r] += av * w0; acc1[r] += av * w1;
            }
        }
    }
    float4_t a1lo = *(const float4_t*)&a[f0];
    float4_t a1hi = *(const float4_t*)&a[f0 + 4];
    float4_t a2lo = *(const float4_t*)&a[128 + f0];
    float4_t a2hi = *(const float4_t*)&a[128 + f0 + 4];
    #pragma unroll
    for (int r = 0; r < 2; ++r) {
        const int row  = gr0 + r0 + r;
        const int rloc = row & 4095;
        #pragma unroll
        for (int c = 0; c < 4; ++c) {
            hT[(size_t)b * (128 * 4096) + (size_t)(f0 + c) * 4096 + rloc]     = (_Float16)acc0[r][c];
            hT[(size_t)b * (128 * 4096) + (size_t)(f0 + 4 + c) * 4096 + rloc] = (_Float16)acc1[r][c];
        }
        float p1 = acc0[r][0]*a1lo[0] + acc0[r][1]*a1lo[1] + acc0[r][2]*a1lo[2] + acc0[r][3]*a1lo[3]
                 + acc1[r][0]*a1hi[0] + acc1[r][1]*a1hi[1] + acc1[r][2]*a1hi[2] + acc1[r][3]*a1hi[3];
        float p2 = acc0[r][0]*a2lo[0] + acc0[r][1]*a2lo[1] + acc0[r][2]*a2lo[2] + acc0[r][3]*a2lo[3]
                 + acc1[r][0]*a2hi[0] + acc1[r][1]*a2hi[1] + acc1[r][2]*a2hi[2] + acc1[r][3]*a2hi[3];
        #pragma unroll
        for (int o = 1; o < 16; o <<= 1) { p1 += __shfl_xor(p1, o); p2 += __shfl_xor(p2, o); }
        if ((t & 15) == 0) { s1[row] = p1; s2[row] = p2; }
    }
}

// ---------------- Kernel M: per-batch s2 max ---------------------------------
__global__ __launch_bounds__(256) void k_s2max(const float* __restrict__ s2,
                                               float* __restrict__ s2max) {
    const int b = blockIdx.x, t = threadIdx.x;
    float m = -INFINITY;
    for (int i = t; i < 4096; i += 256) m = fmaxf(m, s2[b * 4096 + i]);
    #pragma unroll
    for (int o = 1; o < 64; o <<= 1) m = fmaxf(m, __shfl_xor(m, o));
    __shared__ float sm[4];
    if ((t & 63) == 0) sm[t >> 6] = m;
    __syncthreads();
    if (t == 0) s2max[b] = fmaxf(fmaxf(sm[0], sm[1]), fmaxf(sm[2], sm[3]));
}

// ---------------- Kernel F: fixed-max attention + P@H ------------------------
// Grid 512 x 256 (2 j-splits x 64 row-blocks x 4 batches) = exactly 2
// resident blocks/CU, single generation. 32 j-iters per block.
// r7 = r6 sync skeleton (B1 data-visible / B2 end-of-read, counted vmcnt,
// all streaming via zero-VGPR gll) + DEEPER adj pipeline: stage_adj(jt+2)
// is issued MID-iter jt, right after lgkmcnt(0) proves the target slot's
// ds_reads are complete (slot jt&1 was just consumed by p-compute).
// In-flight window: mid(jt) -> top-wait(jt+2) ~ 2 iterations ~ 1000 cy,
// covering HBM latency. Steady-state outstanding at the wait is still
// adj(jt+1)[4] + hT(jt+1)[4] = 8 -> vmcnt(8); issue order (hT(jt) older
// than adj(jt+1)) makes the drain exact. LDS = 32+32+8+8 = 80 KB exactly.
__global__ __launch_bounds__(256, 2) void k_flash(const float* __restrict__ adj,
                                                  const _Float16* __restrict__ hT,
                                                  const float* __restrict__ s1,
                                                  const float* __restrict__ s2,
                                                  const float* __restrict__ s2max,
                                                  float* __restrict__ part_acc,
                                                  float* __restrict__ part_l) {
    __shared__ _Float16 hbuf[2][128 * 64];     // 32 KB shared hT dbuf (swizzled)
    __shared__ float    adjbuf[4][2][16 * 64]; // 32 KB wave-private adj dbuf
    __shared__ _Float16 pbuf[4][16 * 64];      // 8 KB wave-private P tiles
    __shared__ float    s2buf[2048];           // 8 KB block j-window of s2

    const int t    = threadIdx.x;
    const int bid  = blockIdx.x;
    const int sp   = bid & 1;                 // j-split (2048 cols each)
    const int rb   = (bid >> 1) & 63;         // 64-row block within batch
    const int b    = bid >> 7;                // batch
    const int w    = t >> 6, lane = t & 63;
    const int quad = lane >> 4, ln15 = lane & 15;
    const int g    = quad;                    // row-group for p-compute
    const int cl   = ln15;                    // col-lane for p-compute
    const int rowb = rb * 64 + w * 16;        // wave's 16-row base
    const float*    adj_w = adj + (size_t)b * 4096 * 4096 + (size_t)rowb * 4096;
    const _Float16* hT_b  = hT + (size_t)b * 128 * 4096;
    const float     s2m   = s2max[b];
    const int jwbase = sp * 2048;
    const int fb7 = ln15 & 7;
    const int NT  = 32;                       // j-tiles per block

    float s1r[4], mh[4];
    #pragma unroll
    for (int L = 0; L < 4; ++L) {
        s1r[L] = s1[b * 4096 + rowb + L * 4 + g];
        mh[L]  = fmaxf(0.f, s1r[L] + s2m);
    }

    // ---- stage s2 window once (register path; visible after B1(0)) ----
    *(float4_t*)&s2buf[t * 8]     = *(const float4_t*)&s2[(size_t)b * 4096 + jwbase + t * 8];
    *(float4_t*)&s2buf[t * 8 + 4] = *(const float4_t*)&s2[(size_t)b * 4096 + jwbase + t * 8 + 4];
    asm volatile("s_waitcnt lgkmcnt(0)" ::: "memory");

    float4_t acc[8] = {};
    float4_t psacc = {0.f, 0.f, 0.f, 0.f};

    // ---- gll staging (zero VGPR): 4 insts each ----
    auto stage_adj = [&](int slot, int j0) {
        #pragma unroll
        for (int i = 0; i < 4; ++i) {
            const int r = i * 4 + (lane >> 4);
            GLL16(adj_w + (size_t)r * 4096 + j0 + ((lane & 15) << 2),
                  &adjbuf[w][slot][i * 256]);
        }
    };
    auto stage_hT = [&](int slot, int j0) {
        #pragma unroll
        for (int i = 0; i < 4; ++i) {
            const int f0r = (w * 4 + i) * 8;          // 8 f-rows per inst
            const int f   = f0r + (lane >> 3);
            const int sch = (lane & 7) ^ (f & 7);     // inverse-swizzled source
            GLL16(hT_b + ((size_t)f << 12) + j0 + (sch << 3),
                  &hbuf[slot][f0r * 64]);
        }
    };

    asm volatile("" ::: "memory");
    // prologue (issue order matters for vmcnt): hT(0), adj(0), adj(1)
    stage_hT(0, jwbase);
    stage_adj(0, jwbase);
    stage_adj(1, jwbase + 64);

    #pragma unroll 1
    for (int jt = 0; jt < NT; ++jt) {
        const int cur = jt & 1;
        const int j0  = jwbase + jt * 64;
        // ---- top: issue hT(jt+1) into slot cur^1 (freed by B2 of jt-1) ----
        if (jt < NT - 1) stage_hT(cur ^ 1, j0 + 64);
        // counted wait: drain hT(jt)+adj(jt)+older; keep adj(jt+1)+hT(jt+1)
        if (jt < NT - 1) asm volatile("s_waitcnt vmcnt(8)" ::: "memory");
        else             asm volatile("s_waitcnt vmcnt(0)" ::: "memory");
        __builtin_amdgcn_s_barrier();          // B1: slot-cur data visible
        asm volatile("" ::: "memory");
        // ---- p = exp(adj*leaky(s1+s2) - mhat) from LDS -> pbuf ----
        #pragma unroll
        for (int L = 0; L < 4; ++L) {
            float4_t av  = *(const float4_t*)&adjbuf[w][cur][(L * 4 + g) * 64 + cl * 4];
            float4_t s2v = *(const float4_t*)&s2buf[jt * 64 + cl * 4];
            half4_t qv;
            #pragma unroll
            for (int c = 0; c < 4; ++c) {
                float x = s1r[L] + s2v[c];
                float e = x > 0.f ? x : 0.2f * x;
                float p = av[c] > 0.f ? __expf(fmaf(av[c], e, -mh[L])) : 0.f;
                _Float16 q = (_Float16)p;
                qv[c] = q;
                psacc[L] += (float)q;
            }
            const int r     = L * 4 + g;
            const int c0    = cl * 4;
            const int chunk = (c0 >> 3) ^ (r & 7);
            *(half4_t*)&pbuf[w][r * 64 + chunk * 8 + (c0 & 7)] = qv;
        }
        // drain this wave's LDS ops (pbuf writes AND adjbuf/s2buf reads)
        asm volatile("s_waitcnt lgkmcnt(0)" ::: "memory");
        // ---- mid-iter: adj(jt+2) into just-freed slot cur (2-iter flight) --
        if (jt < NT - 2) stage_adj(cur, j0 + 128);
        asm volatile("" ::: "memory");
        // ---- A-frags from pbuf, B-frags from hbuf[cur], MFMA ----
        half8 afrag[2];
        #pragma unroll
        for (int kc = 0; kc < 2; ++kc) {
            const int chunk = ((kc << 2) + quad) ^ (ln15 & 7);
            afrag[kc] = *(const half8*)&pbuf[w][ln15 * 64 + chunk * 8];
        }
        #pragma unroll
        for (int nt = 0; nt < 8; ++nt) {
            #pragma unroll
            for (int kc = 0; kc < 2; ++kc) {
                const int fb = nt * 16 + ln15;
                half8 bfrag = *(const half8*)&hbuf[cur][fb * 64 + ((((kc << 2) + quad) ^ fb7) << 3)];
                acc[nt] = __builtin_amdgcn_mfma_f32_16x16x32_f16(afrag[kc], bfrag, acc[nt], 0, 0, 0);
            }
        }
        // ---- B2: all waves done reading slot cur -> writable next iter ----
        if (jt < NT - 1) {
            asm volatile("" ::: "memory");
            __builtin_amdgcn_s_barrier();
        }
    }

    // ---- epilogue: reduce l within each 16-lane group, write partials ----
    #pragma unroll
    for (int o = 1; o < 16; o <<= 1) {
        #pragma unroll
        for (int L = 0; L < 4; ++L) psacc[L] += __shfl_xor(psacc[L], o);
    }
    const size_t growb = (size_t)b * 4096 + rowb;
    if (cl == 0) {
        #pragma unroll
        for (int L = 0; L < 4; ++L)
            part_l[(size_t)sp * 16384 + growb + L * 4 + g] = psacc[L];
    }
    float* pacc = part_acc + (size_t)sp * 16384 * 128;
    #pragma unroll
    for (int nt = 0; nt < 8; ++nt) {
        #pragma unroll
        for (int reg = 0; reg < 4; ++reg) {
            pacc[(growb + quad * 4 + reg) * 128 + nt * 16 + ln15] = acc[nt][reg];
        }
    }
}

// ---------------- Kernel E: sum 2 j-split partials, normalize, elu -----------
__global__ __launch_bounds__(256) void k_combine(const float* __restrict__ part_acc,
                                                 const float* __restrict__ part_l,
                                                 float* __restrict__ out) {
    const int idx = blockIdx.x * 256 + threadIdx.x;   // 0..524287
    const int e0  = idx * 4;
    const int gr  = e0 >> 7;
    float l = part_l[gr] + part_l[16384 + gr];
    float4_t a0 = *(const float4_t*)&part_acc[e0];
    float4_t a1 = *(const float4_t*)&part_acc[2097152 + e0];
    float4_t s  = a0 + a1;
    float rl = 1.f / l;
    float4_t o;
    #pragma unroll
    for (int c = 0; c < 4; ++c) {
        float v = s[c] * rl;
        o[c] = v > 0.f ? v : expm1f(v);
    }
    *(float4_t*)&((float*)out)[e0] = o;
}

extern "C" void kernel_launch(void* const* d_in, const int* in_sizes, int n_in,
                              void* d_out, int out_size, void* d_ws, size_t ws_size,
                              hipStream_t stream) {
    const float* inp = (const float*)d_in[0];   // (4,4096,256)
    const float* adj = (const float*)d_in[1];   // (4,4096,4096)
    const float* W   = (const float*)d_in[2];   // (256,128)
    const float* a   = (const float*)d_in[3];   // (256,1)
    float* out = (float*)d_out;                 // (4,4096,128)

    char* wsb = (char*)d_ws;
    _Float16* hT       = (_Float16*)(wsb);                // 4 MB
    float*    s1       = (float*)(wsb + 4194304);         // 64 KB
    float*    s2       = (float*)(wsb + 4259840);         // 64 KB
    float*    s2max    = (float*)(wsb + 4325376);         // 256 B
    float*    part_l   = (float*)(wsb + 4325632);         // 128 KB (2 splits)
    float*    part_acc = (float*)(wsb + 4587776);         // 16 MB (2 splits)

    hipLaunchKernelGGL(k_prep,    dim3(512),  dim3(256), 0, stream, inp, W, a, s1, s2, hT);
    hipLaunchKernelGGL(k_s2max,   dim3(4),    dim3(256), 0, stream, s2, s2max);
    hipLaunchKernelGGL(k_flash,   dim3(512),  dim3(256), 0, stream, adj, hT, s1, s2, s2max,
                       part_acc, part_l);
    hipLaunchKernelGGL(k_combine, dim3(2048), dim3(256), 0, stream, part_acc, part_l, out);
}